// Round 1
// 872.805 us; speedup vs baseline: 1.2484x; 1.2484x over previous
//
#include <hip/hip_runtime.h>
#include <hip/hip_bf16.h>

#define N_NODES 50000
#define N_EDGES 800000
#define D_NODE  128
#define D_EDGE  64
#define D_GLOB  64
#define D_IN    384
#define D_OUT   128
#define LN2F    0.69314718055994531f

// padded K pitch for the LDS A-tile in the fallback kernel
#define APITCH  392

typedef __attribute__((ext_vector_type(4))) float  floatx4;
typedef __attribute__((ext_vector_type(8))) short  shortx8;

#define MFMA16 __builtin_amdgcn_mfma_f32_16x16x32_bf16

// load 8 consecutive fp32 (32 B, caller guarantees alignment) -> 8 bf16 (RNE)
__device__ __forceinline__ shortx8 cvt8_bf16(const float* __restrict__ p) {
    floatx4 a = *(const floatx4*)p;
    floatx4 b = *(const floatx4*)(p + 4);
    shortx8 r;
    union { __hip_bfloat16 h; short s; } u;
    #pragma unroll
    for (int j = 0; j < 4; ++j) {
        u.h = __float2bfloat16(a[j]); r[j]     = u.s;
        u.h = __float2bfloat16(b[j]); r[j + 4] = u.s;
    }
    return r;
}

// ===========================================================================
// Kernel P1: Psrc = node @ W[:, 0:128]^T, Pdst = node @ W[:, 128:256]^T
// Transposed MFMA: A = W-part (M = out-channel n), B = node tile (N = node i).
// D layout: col(lane&15) = i, row(quad*4+r) = n  -> lane stores 4 consecutive
// n of one node row: dwordx4 stores.
// grid = 782 node-tiles * 2 tables = 1564 blocks, 256 threads.
// ===========================================================================
__global__ __launch_bounds__(256, 2)
void proj_node_kernel(const float* __restrict__ node,
                      const float* __restrict__ W,
                      float* __restrict__ Psrc,
                      float* __restrict__ Pdst)
{
    const int bid   = blockIdx.x;
    const int table = bid & 1;
    const int i0    = (bid >> 1) * 64;
    float* __restrict__ P = table ? Pdst : Psrc;
    const int coloff = table * D_NODE;

    const int tid  = threadIdx.x;
    const int wave = tid >> 6;
    const int lane = tid & 63;
    const int nlo  = lane & 15;
    const int quad = lane >> 4;

    // A frags: W[n][coloff + kc*32 + quad*8 .. +8]
    shortx8 wfrag[2][4];
    #pragma unroll
    for (int nt = 0; nt < 2; ++nt) {
        const int n = wave * 32 + nt * 16 + nlo;
        #pragma unroll
        for (int kc = 0; kc < 4; ++kc)
            wfrag[nt][kc] = cvt8_bf16(W + (size_t)n * D_IN + coloff + kc * 32 + quad * 8);
    }

    floatx4 acc[2][4];
    #pragma unroll
    for (int nt = 0; nt < 2; ++nt)
        #pragma unroll
        for (int it = 0; it < 4; ++it)
            acc[nt][it] = (floatx4){0.f, 0.f, 0.f, 0.f};

    #pragma unroll
    for (int kc = 0; kc < 4; ++kc) {
        #pragma unroll
        for (int it = 0; it < 4; ++it) {
            int i = i0 + it * 16 + nlo;
            if (i >= N_NODES) i = N_NODES - 1;          // clamp: tail reads valid row
            shortx8 b = cvt8_bf16(node + (size_t)i * D_NODE + kc * 32 + quad * 8);
            acc[0][it] = MFMA16(wfrag[0][kc], b, acc[0][it], 0, 0, 0);
            acc[1][it] = MFMA16(wfrag[1][kc], b, acc[1][it], 0, 0, 0);
        }
    }

    #pragma unroll
    for (int it = 0; it < 4; ++it) {
        const int i = i0 + it * 16 + nlo;
        if (i < N_NODES) {
            #pragma unroll
            for (int nt = 0; nt < 2; ++nt) {
                const int n0 = wave * 32 + nt * 16 + quad * 4;
                *(floatx4*)(P + (size_t)i * D_OUT + n0) = acc[nt][it];
            }
        }
    }
}

// ===========================================================================
// Kernel P2: Pglob = globf @ W[:, 320:384]^T   (256 x 128, tiny: 4 blocks)
// ===========================================================================
__global__ __launch_bounds__(256, 2)
void proj_glob_kernel(const float* __restrict__ globf,
                      const float* __restrict__ W,
                      float* __restrict__ Pglob)
{
    const int i0   = blockIdx.x * 64;
    const int tid  = threadIdx.x;
    const int wave = tid >> 6;
    const int lane = tid & 63;
    const int nlo  = lane & 15;
    const int quad = lane >> 4;

    shortx8 wfrag[2][2];
    #pragma unroll
    for (int nt = 0; nt < 2; ++nt) {
        const int n = wave * 32 + nt * 16 + nlo;
        #pragma unroll
        for (int kc = 0; kc < 2; ++kc)
            wfrag[nt][kc] = cvt8_bf16(W + (size_t)n * D_IN + 320 + kc * 32 + quad * 8);
    }

    floatx4 acc[2][4];
    #pragma unroll
    for (int nt = 0; nt < 2; ++nt)
        #pragma unroll
        for (int it = 0; it < 4; ++it)
            acc[nt][it] = (floatx4){0.f, 0.f, 0.f, 0.f};

    #pragma unroll
    for (int kc = 0; kc < 2; ++kc) {
        #pragma unroll
        for (int it = 0; it < 4; ++it) {
            const int i = i0 + it * 16 + nlo;
            shortx8 b = cvt8_bf16(globf + (size_t)i * D_GLOB + kc * 32 + quad * 8);
            acc[0][it] = MFMA16(wfrag[0][kc], b, acc[0][it], 0, 0, 0);
            acc[1][it] = MFMA16(wfrag[1][kc], b, acc[1][it], 0, 0, 0);
        }
    }

    #pragma unroll
    for (int it = 0; it < 4; ++it) {
        const int i = i0 + it * 16 + nlo;
        #pragma unroll
        for (int nt = 0; nt < 2; ++nt) {
            const int n0 = wave * 32 + nt * 16 + quad * 4;
            *(floatx4*)(Pglob + (size_t)i * D_OUT + n0) = acc[nt][it];
        }
    }
}

// ===========================================================================
// Kernel E: per-edge. No LDS, no barrier.
//   out[e] = softplus( edgef[e] @ We^T + Psrc[src] + Pdst[dst] + Pglob[b] ) - ln2
// Transposed MFMA (A = We rows as M, edges as N): lane's accumulator holds
// 4 consecutive output channels of one edge -> 16B dwordx4 gathers and stores.
// grid = 12500 blocks x 256 threads; wave owns a 32-channel slice of 64 edges.
// ===========================================================================
__global__ __launch_bounds__(256, 2)
void edge_fused_kernel(const float* __restrict__ edgef,
                       const int* __restrict__ eidx,
                       const int* __restrict__ batch,
                       const float* __restrict__ W,
                       const float* __restrict__ Psrc,
                       const float* __restrict__ Pdst,
                       const float* __restrict__ Pglob,
                       float* __restrict__ out)
{
    const int tid  = threadIdx.x;
    const int e0   = blockIdx.x * 64;
    const int wave = tid >> 6;
    const int lane = tid & 63;
    const int nlo  = lane & 15;
    const int quad = lane >> 4;

    // int64-vs-int32 layout sniff (identical to proven baseline; deterministic).
    const int is64 = ((eidx[1] | eidx[3] | eidx[5] | eidx[7] |
                       eidx[9] | eidx[11] | eidx[13] | eidx[15]) == 0) ? 1 : 0;

    // ---- index loads first: get the gather chains started early ----
    int src[4], dst[4], bat[4];
    #pragma unroll
    for (int et = 0; et < 4; ++et) {
        const int e = e0 + et * 16 + nlo;
        src[et] = eidx[(size_t)e << is64];
        dst[et] = eidx[(size_t)(N_EDGES + e) << is64];
    }
    #pragma unroll
    for (int et = 0; et < 4; ++et)
        bat[et] = batch[(size_t)src[et] << is64];

    // ---- B frags: edgef tile, streamed (16 rows x 128B per instruction) ----
    shortx8 bfrag[4][2];
    #pragma unroll
    for (int et = 0; et < 4; ++et) {
        const float* row = edgef + (size_t)(e0 + et * 16 + nlo) * D_EDGE;
        #pragma unroll
        for (int kc = 0; kc < 2; ++kc)
            bfrag[et][kc] = cvt8_bf16(row + kc * 32 + quad * 8);
    }

    // ---- A frags: We = W[:, 256:320] (L1/L2-resident after first block) ----
    shortx8 wfrag[2][2];
    #pragma unroll
    for (int nt = 0; nt < 2; ++nt) {
        const int n = wave * 32 + nt * 16 + nlo;
        #pragma unroll
        for (int kc = 0; kc < 2; ++kc)
            wfrag[nt][kc] = cvt8_bf16(W + (size_t)n * D_IN + 256 + kc * 32 + quad * 8);
    }

    floatx4 acc[2][4];
    #pragma unroll
    for (int nt = 0; nt < 2; ++nt)
        #pragma unroll
        for (int et = 0; et < 4; ++et)
            acc[nt][et] = (floatx4){0.f, 0.f, 0.f, 0.f};

    #pragma unroll
    for (int kc = 0; kc < 2; ++kc) {
        #pragma unroll
        for (int et = 0; et < 4; ++et) {
            acc[0][et] = MFMA16(wfrag[0][kc], bfrag[et][kc], acc[0][et], 0, 0, 0);
            acc[1][et] = MFMA16(wfrag[1][kc], bfrag[et][kc], acc[1][et], 0, 0, 0);
        }
    }

    // ---- epilogue: 3 x dwordx4 gather-adds + softplus + dwordx4 nt store ----
    #pragma unroll
    for (int et = 0; et < 4; ++et) {
        const int e = e0 + et * 16 + nlo;
        const float* ps = Psrc  + (size_t)src[et] * D_OUT;
        const float* pd = Pdst  + (size_t)dst[et] * D_OUT;
        const float* pg = Pglob + (size_t)bat[et] * D_OUT;
        #pragma unroll
        for (int nt = 0; nt < 2; ++nt) {
            const int n0 = wave * 32 + nt * 16 + quad * 4;
            floatx4 g1 = *(const floatx4*)(ps + n0);
            floatx4 g2 = *(const floatx4*)(pd + n0);
            floatx4 g3 = *(const floatx4*)(pg + n0);
            floatx4 r;
            #pragma unroll
            for (int j = 0; j < 4; ++j) {
                const float h = acc[nt][et][j] + g1[j] + g2[j] + g3[j];
                const float t = __expf(-fabsf(h));
                r[j] = fmaxf(h, 0.f) + __logf(1.f + t) - LN2F;
            }
            // write-only stream: nontemporal keeps L2 free for the gather tables
            __builtin_nontemporal_store(r, (floatx4*)(out + (size_t)e * D_OUT + n0));
        }
    }
}

// ===========================================================================
// Fallback: the previous proven kernel (used only if workspace is too small)
// ===========================================================================
__global__ __launch_bounds__(256, 2)
void edge_mlp_kernel(const float* __restrict__ node,
                     const float* __restrict__ edgef,
                     const float* __restrict__ globf,
                     const int* __restrict__ eidx,
                     const int* __restrict__ batch,
                     const float* __restrict__ W,
                     float* __restrict__ out)
{
    __shared__ short A_lds[64 * APITCH];

    const int tid = threadIdx.x;
    const int e0  = blockIdx.x * 64;

    const int is64 = ((eidx[1] | eidx[3] | eidx[5] | eidx[7] |
                       eidx[9] | eidx[11] | eidx[13] | eidx[15]) == 0) ? 1 : 0;

    #pragma unroll
    for (int i = 0; i < 12; ++i) {
        int g       = tid + i * 256;
        int e_local = g / 48;
        int off     = (g - e_local * 48) * 8;
        int e       = e0 + e_local;
        const float* srcp;
        if (off < 128) {
            int s = eidx[(size_t)e << is64];
            srcp = node + (size_t)s * D_NODE + off;
        } else if (off < 256) {
            int d = eidx[(size_t)(N_EDGES + e) << is64];
            srcp = node + (size_t)d * D_NODE + (off - 128);
        } else if (off < 320) {
            srcp = edgef + (size_t)e * D_EDGE + (off - 256);
        } else {
            int s = eidx[(size_t)e << is64];
            int b = batch[(size_t)s << is64];
            srcp = globf + (size_t)b * D_GLOB + (off - 320);
        }
        *(shortx8*)(&A_lds[e_local * APITCH + off]) = cvt8_bf16(srcp);
    }

    const int wave = tid >> 6;
    const int lane = tid & 63;
    const int nlo  = lane & 15;
    const int quad = lane >> 4;

    shortx8 bfrag[12][2];
    #pragma unroll
    for (int kc = 0; kc < 12; ++kc) {
        #pragma unroll
        for (int nt = 0; nt < 2; ++nt) {
            int n = wave * 32 + nt * 16 + nlo;
            bfrag[kc][nt] = cvt8_bf16(W + (size_t)n * D_IN + kc * 32 + quad * 8);
        }
    }

    floatx4 acc[4][2];
    #pragma unroll
    for (int mt = 0; mt < 4; ++mt)
        #pragma unroll
        for (int nt = 0; nt < 2; ++nt)
            acc[mt][nt] = (floatx4){0.f, 0.f, 0.f, 0.f};

    __syncthreads();

    #pragma unroll
    for (int kc = 0; kc < 12; ++kc) {
        #pragma unroll
        for (int mt = 0; mt < 4; ++mt) {
            shortx8 afrag = *(const shortx8*)(
                &A_lds[(mt * 16 + nlo) * APITCH + kc * 32 + quad * 8]);
            #pragma unroll
            for (int nt = 0; nt < 2; ++nt) {
                acc[mt][nt] = MFMA16(afrag, bfrag[kc][nt], acc[mt][nt], 0, 0, 0);
            }
        }
    }

    #pragma unroll
    for (int mt = 0; mt < 4; ++mt) {
        #pragma unroll
        for (int nt = 0; nt < 2; ++nt) {
            int n = wave * 32 + nt * 16 + nlo;
            #pragma unroll
            for (int r = 0; r < 4; ++r) {
                int e = e0 + mt * 16 + quad * 4 + r;
                float h  = acc[mt][nt][r];
                float t  = __expf(-fabsf(h));
                float sp = fmaxf(h, 0.0f) + __logf(1.0f + t);
                out[(size_t)e * D_OUT + n] = sp - LN2F;
            }
        }
    }
}

extern "C" void kernel_launch(void* const* d_in, const int* in_sizes, int n_in,
                              void* d_out, int out_size, void* d_ws, size_t ws_size,
                              hipStream_t stream) {
    const float* node  = (const float*)d_in[0];
    const float* edgef = (const float*)d_in[1];
    const float* globf = (const float*)d_in[2];
    const int*   eidx  = (const int*)d_in[3];
    const int*   batch = (const int*)d_in[4];
    const float* W     = (const float*)d_in[5];
    float*       out   = (float*)d_out;

    const size_t PN   = (size_t)N_NODES * D_OUT;                 // 6.4M floats
    const size_t need = (2 * PN + 256 * D_OUT) * sizeof(float);  // ~51.4 MB

    if (ws_size >= need) {
        float* Psrc  = (float*)d_ws;
        float* Pdst  = Psrc + PN;
        float* Pglob = Pdst + PN;
        // 782 node-tiles x 2 tables; ceil(50000/64) = 782
        proj_node_kernel<<<dim3(782 * 2), dim3(256), 0, stream>>>(node, W, Psrc, Pdst);
        proj_glob_kernel<<<dim3(4), dim3(256), 0, stream>>>(globf, W, Pglob);
        edge_fused_kernel<<<dim3(N_EDGES / 64), dim3(256), 0, stream>>>(
            edgef, eidx, batch, W, Psrc, Pdst, Pglob, out);
    } else {
        edge_mlp_kernel<<<dim3(N_EDGES / 64), dim3(256), 0, stream>>>(
            node, edgef, globf, eidx, batch, W, out);
    }
}